// Round 9
// baseline (102.913 us; speedup 1.0000x reference)
//
#include <hip/hip_runtime.h>
#include <math.h>

// PostProcess: B=16, Q=2048, C=2. SINGLE kernel, grid = B*8 x 1024 (R8 structure).
// R9 delta vs R8: minimal-coherence protocol. Matrix stores are RELAXED+AGENT
// (sc1 scope bits, straight to coherence point, no wbl2); spin uses RELAXED loads
// (no per-iteration L2 invalidate); ONE acquire after spin before matrix reads.
// ws: flags u32[128]@0 | mat u32[16][17408]@1024   (~1.12 MB)

#define QN    2048
#define NS    1024      // fast-path max valid boxes (E[M]=562, sd~20; M>NS ~23 sigma)
#define MATW  17408     // ragged u32 words/image = 64 * sum_{wb<16}(32-2wb)
#define MAGIC 0x5ca1ab1eu

__device__ __forceinline__ int rb32(int wb) { return 64 * wb * (33 - wb); }

__device__ __forceinline__ unsigned long long shfl_xor_u64(unsigned long long x, int m) {
    int lo = __shfl_xor((int)(unsigned)(x & 0xffffffffull), m, 64);
    int hi = __shfl_xor((int)(unsigned)(x >> 32), m, 64);
    return ((unsigned long long)(unsigned)hi << 32) | (unsigned)lo;
}

// ascending key order == score desc, idx asc (stable); invalid -> tail. Validity
// returned explicitly (valid key's top bit is SET -- R3 bug).
__device__ __forceinline__ unsigned long long score_key(float2 l, int q, bool* valid_out) {
    float mx = fmaxf(l.x, l.y), mn = fminf(l.x, l.y);
    float e = expf(mn - mx);
    float score = 1.0f / (1.0f + e);                 // max softmax prob (exact ref order)
    bool valid = (l.x >= l.y) && (score >= 0.7f);    // argmax tie -> class 0
    *valid_out = valid;
    unsigned sbits = valid ? __float_as_uint(score) : 0u;
    return ((unsigned long long)(~sbits) << 32) | (unsigned)q;
}

__global__ __launch_bounds__(1024) void kfused(
    const float* __restrict__ logits, const float* __restrict__ pboxes,
    const int* __restrict__ img_h_p, const int* __restrict__ img_w_p,
    unsigned* __restrict__ wflag, unsigned* __restrict__ wmat,
    float* __restrict__ out, int B)
{
    __shared__ __align__(16) char smem[32904];
    unsigned long long* skey = (unsigned long long*)smem;
    float* sx1 = (float*)(smem + 8192);
    float* sy1 = (float*)(smem + 12288);
    float* sx2 = (float*)(smem + 16384);
    float* sy2 = (float*)(smem + 20480);
    float* sar = (float*)(smem + 24576);
    unsigned short* sidxl = (unsigned short*)(smem + 28672);
    unsigned char* keepq = (unsigned char*)(smem + 30720);
    unsigned* skm = (unsigned*)(smem + 32768);
    int* sMp = (int*)(smem + 32896);

    const int blk = blockIdx.x;
    const int b = blk % B, slice = blk / B;
    const int tid = threadIdx.x, lane = tid & 63, wave = tid >> 6;
    const float sw = (float)(*img_w_p), sh = (float)(*img_h_p);

    if (tid == 0) *sMp = 0;
    keepq[tid] = 0; keepq[tid + 1024] = 0;
    if (tid < 32) skm[tid] = 0;
    __syncthreads();

    // ---- compact valid keys (ballot compaction; verified R4-R8) ----
    const unsigned long long lmask_lt = (1ull << lane) - 1ull;
#pragma unroll
    for (int qq = 0; qq < 2; ++qq) {
        int q = tid + qq * 1024;
        float2 l = ((const float2*)logits)[b * QN + q];
        bool valid;
        unsigned long long key = score_key(l, q, &valid);
        unsigned long long mb = __ballot(valid);
        int base = 0;
        if (lane == 0 && mb) base = atomicAdd(sMp, __popcll(mb));
        base = __shfl(base, 0, 64);
        if (valid) {
            int slot = base + __popcll(mb & lmask_lt);
            if (slot < NS) skey[slot] = key;
        }
    }
    __syncthreads();
    const int M = *sMp;

    if (M <= NS) {
        // ---- register bitonic sort of NS u64, 1 elem/thread (verified R4/R5/R8) ----
        unsigned long long v = (tid < M) ? skey[tid] : ~0ull;
        __syncthreads();
#pragma unroll
        for (int k = 2; k <= 64; k <<= 1) {
            bool dir = ((tid & k) == 0);
#pragma unroll
            for (int j = k >> 1; j > 0; j >>= 1) {
                unsigned long long o = shfl_xor_u64(v, j);
                bool takeMin = (dir == ((tid & j) == 0));
                v = ((v < o) == takeMin) ? v : o;
            }
        }
        for (int k = 128; k <= NS; k <<= 1) {
            bool dir = ((tid & k) == 0);
            for (int j = k >> 1; j >= 64; j >>= 1) {
                skey[tid] = v;
                __syncthreads();
                unsigned long long o = skey[tid ^ j];
                bool takeMin = (dir == ((tid & j) == 0));
                v = ((v < o) == takeMin) ? v : o;
                __syncthreads();
            }
#pragma unroll
            for (int j = 32; j > 0; j >>= 1) {
                unsigned long long o = shfl_xor_u64(v, j);
                bool takeMin = (dir == ((tid & j) == 0));
                v = ((v < o) == takeMin) ? v : o;
            }
        }
        int qi = (int)((unsigned)v & 0xffffu);
        sidxl[tid] = (unsigned short)qi;
        float x1 = 0.f, y1 = 0.f, x2 = 0.f, y2 = 0.f, ar = 0.f;
        if (tid < M) {
            float4 pb = ((const float4*)pboxes)[b * QN + qi];
            x1 = (pb.x - 0.5f * pb.z) * sw;
            y1 = (pb.y - 0.5f * pb.w) * sh;
            x2 = (pb.x + 0.5f * pb.z) * sw;
            y2 = (pb.y + 0.5f * pb.w) * sh;
            ar = fmaxf(x2 - x1, 0.f) * fmaxf(y2 - y1, 0.f);
        }
        sx1[tid] = x1; sy1[tid] = y1; sx2[tid] = x2; sy2[tid] = y2; sar[tid] = ar;
        __syncthreads();

        // ---- matrix slice; stores RELAXED+AGENT (scope bits only, no cache ops) ----
        unsigned* mat = wmat + (long)b * MATW;
        const int NG = (M + 3) >> 2;
        const int W64 = (M + 63) >> 6;
        for (int gi = slice * 16 + wave; gi < NG; gi += 128) {
            const int g = gi << 2;
            const int nr = min(4, M - g);
            const int wb = g >> 6;
            const int rl = 32 - 2 * wb;
            float ax1[4], ay1[4], ax2[4], ay2[4], aar[4];
            int rbase[4];
#pragma unroll
            for (int r = 0; r < 4; ++r) {
                int i = g + min(r, nr - 1);
                ax1[r] = sx1[i]; ay1[r] = sy1[i];
                ax2[r] = sx2[i]; ay2[r] = sy2[i]; aar[r] = sar[i];
                rbase[r] = rb32(wb) + ((g + r) & 63) * rl;
            }
            for (int w = wb; w < W64; ++w) {
                int j = (w << 6) | lane;
                float bx1 = sx1[j], by1 = sy1[j], bx2 = sx2[j], by2 = sy2[j], bar = sar[j];
#pragma unroll
                for (int r = 0; r < 4; ++r) {
                    float ltx = fmaxf(ax1[r], bx1), lty = fmaxf(ay1[r], by1);
                    float rbx = fminf(ax2[r], bx2), rby = fminf(ay2[r], by2);
                    float wx = fmaxf(rbx - ltx, 0.f), wy = fmaxf(rby - lty, 0.f);
                    float inter = wx * wy;
                    float uni = aar[r] + bar - inter;       // exact ref op order
                    float iou = inter / fmaxf(uni, 1e-9f);  // exact IEEE div
                    bool sup = (iou > 0.5f) && (j > g + r);
                    unsigned long long bal = __ballot(sup);
                    if (lane == 0 && r < nr)
                        __hip_atomic_store(
                            (unsigned long long*)(mat + rbase[r] + 2 * (w - wb)), bal,
                            __ATOMIC_RELAXED, __HIP_MEMORY_SCOPE_AGENT);
                }
            }
        }
        __syncthreads();   // all matrix stores issued (barrier drains vmcnt)
        if (tid == 0)
            __hip_atomic_store(&wflag[b * 8 + slice], MAGIC,
                               __ATOMIC_RELEASE, __HIP_MEMORY_SCOPE_AGENT);
        if (slice != 0) return;

        // ---- consumer: RELAXED spin (no per-iter inv), ONE acquire, then scan ----
        if (wave == 0) {
            const unsigned* fp = &wflag[b * 8 + (lane & 7)];
            for (;;) {
                unsigned f = (lane < 8)
                    ? __hip_atomic_load(fp, __ATOMIC_RELAXED, __HIP_MEMORY_SCOPE_AGENT)
                    : MAGIC;
                if (__all(f == MAGIC)) break;
                __builtin_amdgcn_s_sleep(2);
            }
            // single acquire: invalidate stale L1/L2 once before matrix reads
            (void)__hip_atomic_load(&wflag[b * 8], __ATOMIC_ACQUIRE,
                                    __HIP_MEMORY_SCOPE_AGENT);

            const unsigned* gm = wmat + (long)b * MATW;
            unsigned rem = 0;
            const int Ms = __builtin_amdgcn_readfirstlane(M);
            const int C = (Ms + 31) >> 5;
            unsigned rcur[32], rnxt[32];
            if (C > 0) {
                int Lc = min(tid, 31);
#pragma unroll
                for (int t = 0; t < 32; ++t) rcur[t] = gm[Lc + t * 32];
            }
            for (int c = 0; c < C; ++c) {
                if (c + 1 < C) {
                    int cn = c + 1, wbn = cn >> 1, rln = 32 - 2 * wbn;
                    int Lcn = min(max(tid, 2 * wbn), 31);
                    int rb0n = rb32(wbn) + ((cn & 1) << 5) * rln + (Lcn - 2 * wbn);
#pragma unroll
                    for (int t = 0; t < 32; ++t) rnxt[t] = gm[rb0n + t * rln];
                }
                unsigned rw = (unsigned)__builtin_amdgcn_readlane((int)rem, c);
                unsigned keepmask = 0;
                int lim = min(32, Ms - (c << 5));
#pragma unroll
                for (int t = 0; t < 32; ++t) {
                    if (t < lim && !((rw >> t) & 1u)) {   // wave-uniform predicate
                        keepmask |= (1u << t);
                        rem |= rcur[t];
                        rw |= (unsigned)__builtin_amdgcn_readlane((int)rcur[t], c);
                    }
                }
                if (tid == 0) skm[c] = keepmask;
                if (c + 1 < C) {
#pragma unroll
                    for (int t = 0; t < 32; ++t) rcur[t] = rnxt[t];
                }
            }
        }
        __syncthreads();
        for (int s = tid; s < M; s += 1024)
            if ((skm[s >> 5] >> (s & 31)) & 1u) keepq[sidxl[s]] = 1;
        __syncthreads();
    } else {
        if (slice != 0) return;
        // ---- Fallback (M > NS, ~never): LDS sort + barrier greedy -> keepq ----
        unsigned long long* skeyF = (unsigned long long*)smem;
        unsigned char* ssupp = (unsigned char*)(smem + 16384);
        for (int q = tid; q < QN; q += 1024) {
            float2 l = ((const float2*)logits)[b * QN + q];
            bool valid;
            skeyF[q] = score_key(l, q, &valid);
        }
        __syncthreads();
        for (int k = 2; k <= QN; k <<= 1)
            for (int j = k >> 1; j > 0; j >>= 1) {
                int i = ((tid & ~(j - 1)) << 1) | (tid & (j - 1));
                int p = i | j;
                bool up = ((i & k) == 0);
                unsigned long long a = skeyF[i], c2 = skeyF[p];
                if ((a > c2) == up) { skeyF[i] = c2; skeyF[p] = a; }
                __syncthreads();
            }
        for (int s = tid; s < M; s += 1024) ssupp[s] = 0;
        __syncthreads();
        for (int i = 0; i < M; ++i) {
            __syncthreads();
            if (ssupp[i]) continue;
            int ia = (unsigned short)(unsigned)skeyF[i];
            float4 pa = ((const float4*)pboxes)[b * QN + ia];
            float ax1 = (pa.x - 0.5f * pa.z) * sw, ay1 = (pa.y - 0.5f * pa.w) * sh;
            float ax2 = (pa.x + 0.5f * pa.z) * sw, ay2 = (pa.y + 0.5f * pa.w) * sh;
            float areaA = fmaxf(ax2 - ax1, 0.f) * fmaxf(ay2 - ay1, 0.f);
            for (int jj = i + 1 + tid; jj < M; jj += 1024) {
                int jb = (unsigned short)(unsigned)skeyF[jj];
                float4 pq = ((const float4*)pboxes)[b * QN + jb];
                float bx1 = (pq.x - 0.5f * pq.z) * sw, by1 = (pq.y - 0.5f * pq.w) * sh;
                float bx2 = (pq.x + 0.5f * pq.z) * sw, by2 = (pq.y + 0.5f * pq.w) * sh;
                float ltx = fmaxf(ax1, bx1), lty = fmaxf(ay1, by1);
                float rbx = fminf(ax2, bx2), rby = fminf(ay2, by2);
                float wx = fmaxf(rbx - ltx, 0.f), wy = fmaxf(rby - lty, 0.f);
                float inter = wx * wy;
                float areaB = fmaxf(bx2 - bx1, 0.f) * fmaxf(by2 - by1, 0.f);
                float uni = areaA + areaB - inter;
                if (inter / fmaxf(uni, 1e-9f) > 0.5f) ssupp[jj] = 1;
            }
        }
        __syncthreads();
        for (int s = tid; s < M; s += 1024)
            if (!ssupp[s]) keepq[(unsigned short)(unsigned)skeyF[s]] = 1;
        __syncthreads();
    }

    // ---- epilogue: all outputs (d_out poisoned every call); consumer blocks only ----
    const long BQ = (long)B * QN;
#pragma unroll
    for (int qq = 0; qq < 2; ++qq) {
        int q = tid + qq * 1024;
        int base = b * QN + q;
        float2 l = ((const float2*)logits)[base];
        float e = expf(fminf(l.x, l.y) - fmaxf(l.x, l.y));
        float score = 1.0f / (1.0f + e);
        float4 pb = ((const float4*)pboxes)[base];
        float x1 = (pb.x - 0.5f * pb.z) * sw, y1 = (pb.y - 0.5f * pb.w) * sh;
        float x2 = (pb.x + 0.5f * pb.z) * sw, y2 = (pb.y + 0.5f * pb.w) * sh;
        int kp = keepq[q];
        out[base] = kp ? score : 0.f;
        out[BQ * 5 + base] = kp ? 1.f : 0.f;
        float4 ob;
        ob.x = kp ? truncf(x1) : 0.f;
        ob.y = kp ? truncf(y1) : 0.f;
        ob.z = kp ? truncf(x2) : 0.f;
        ob.w = kp ? truncf(y2) : 0.f;
        ((float4*)(out + BQ))[base] = ob;
    }
}

extern "C" void kernel_launch(void* const* d_in, const int* in_sizes, int n_in,
                              void* d_out, int out_size, void* d_ws, size_t ws_size,
                              hipStream_t stream) {
    const float* logits = (const float*)d_in[0];
    const float* pboxes = (const float*)d_in[1];
    const int*   img_h  = (const int*)d_in[2];
    const int*   img_w  = (const int*)d_in[3];
    float* out = (float*)d_out;
    const int B = in_sizes[0] / (QN * 2);   // 16

    char* ws = (char*)d_ws;                 // needs ~1.12 MB
    unsigned* wflag = (unsigned*)(ws + 0);
    unsigned* wmat  = (unsigned*)(ws + 1024);

    kfused<<<dim3(B * 8), dim3(1024), 0, stream>>>(logits, pboxes, img_h, img_w,
                                                   wflag, wmat, out, B);
}